// Round 11
// baseline (417.654 us; speedup 1.0000x reference)
//
#include <hip/hip_runtime.h>
#include <math.h>

#define N_NODES 30000
#define E_EDGES 480000
#define EP (E_EDGES + N_NODES) /* 510000 edges incl self loops */
#define IN_CH 128
#define HID 32
#define HEADS 8
#define HC 256
#define BN_EPS 1e-5f
#define NEG_SLOPE 0.2f
#define SCAN_NB ((N_NODES + 1023) / 1024) /* 30 */
#define BN_ROWS 128
#define BN_NBLK ((N_NODES + BN_ROWS - 1) / BN_ROWS) /* 235 */

typedef __attribute__((ext_vector_type(8))) short bf16x8;
typedef __attribute__((ext_vector_type(4))) float f32x4;

__device__ __forceinline__ float elu_f(float x) { return x > 0.f ? x : __expf(x) - 1.f; }
__device__ __forceinline__ float lrelu_f(float x) { return x >= 0.f ? x : NEG_SLOPE * x; }
__device__ __forceinline__ float bf2f(unsigned short u) {
    return __uint_as_float(((unsigned)u) << 16);
}
__device__ __forceinline__ unsigned short f2bf(float f) {
    unsigned u = __float_as_uint(f);
    return (unsigned short)((u + 0x7fffu + ((u >> 16) & 1u)) >> 16);
}

// ---------------- all weights fp32 -> bf16 transposed, one dispatch ----------------
__global__ void wt_all_kernel(const float* __restrict__ W1, const float* __restrict__ W2,
                              const float* __restrict__ lW1,
                              unsigned short* __restrict__ wt1,
                              unsigned short* __restrict__ wt2,
                              unsigned short* __restrict__ wtm) {
    int i = blockIdx.x * 256 + threadIdx.x;
    if (i < IN_CH * HC) {
        int k = i >> 8, n = i & 255;
        wt1[(size_t)n * IN_CH + k] = f2bf(W1[i]);
    } else if (i < IN_CH * HC + HC * HC) {
        int j = i - IN_CH * HC;
        int k = j >> 8, n = j & 255;
        wt2[(size_t)n * HC + k] = f2bf(W2[j]);
    } else if (i < IN_CH * HC + HC * HC + HC * HID) {
        int j = i - IN_CH * HC - HC * HC;
        int k = j >> 5, n = j & 31;
        wtm[(size_t)n * HC + k] = f2bf(lW1[j]);
    }
}

// ---------------- direct-fragment MFMA GEMM + fused al epilogue ----------------
// R11 shape: block = 16 rows; 4 waves split N (wave w -> col-tiles 4w..4w+3 =
// heads 2w,2w+1). 1875 blocks (~29 waves/CU), 4 acc tiles/wave (16 AGPRs),
// 5 loads + 4 MFMAs per K-step. No LDS, no barriers.
__global__ __launch_bounds__(256) void gemm_direct(const float* __restrict__ A32,
                                                   const unsigned short* __restrict__ Abf,
                                                   const unsigned short* __restrict__ Wt,
                                                   unsigned short* __restrict__ C,
                                                   float* __restrict__ al_s,
                                                   float* __restrict__ al_d,
                                                   const float* __restrict__ a_src,
                                                   const float* __restrict__ a_dst,
                                                   int M, int K,
                                                   const float* __restrict__ sc,
                                                   const float* __restrict__ sh) {
    int tid = threadIdx.x;
    int wave = tid >> 6, lane = tid & 63;
    int m = lane & 15, q = lane >> 4;
    int rbase = blockIdx.x * 16;       // M divisible by 16: no row guard needed
    int arow = rbase + m;
    // wave's 4 col-tiles: global tile g = wave*4 + ntl
    const unsigned short* wp = Wt + ((size_t)(wave * 64) + m) * K + q * 8;
    f32x4 acc[4];
#pragma unroll
    for (int i = 0; i < 4; ++i) acc[i] = (f32x4){0.f, 0.f, 0.f, 0.f};

    for (int k0 = 0; k0 < K; k0 += 32) {
        int c0 = k0 + q * 8;
        bf16x8 bfr[4];
#pragma unroll
        for (int ntl = 0; ntl < 4; ++ntl)
            bfr[ntl] = *(const bf16x8*)(wp + (size_t)ntl * 16 * K + k0);
        float4 v0, v1;
        if (A32) {
            const float* ap = A32 + (size_t)arow * K + c0;
            v0 = *(const float4*)ap;
            v1 = *(const float4*)(ap + 4);
        } else {
            uint4 raw = *(const uint4*)(Abf + (size_t)arow * K + c0);
            v0.x = bf2f((unsigned short)raw.x); v0.y = bf2f((unsigned short)(raw.x >> 16));
            v0.z = bf2f((unsigned short)raw.y); v0.w = bf2f((unsigned short)(raw.y >> 16));
            v1.x = bf2f((unsigned short)raw.z); v1.y = bf2f((unsigned short)(raw.z >> 16));
            v1.z = bf2f((unsigned short)raw.w); v1.w = bf2f((unsigned short)(raw.w >> 16));
        }
        if (sc) {
            float4 s0 = *(const float4*)(sc + c0), s1 = *(const float4*)(sc + c0 + 4);
            float4 t0 = *(const float4*)(sh + c0), t1 = *(const float4*)(sh + c0 + 4);
            v0.x = v0.x * s0.x + t0.x; v0.y = v0.y * s0.y + t0.y;
            v0.z = v0.z * s0.z + t0.z; v0.w = v0.w * s0.w + t0.w;
            v1.x = v1.x * s1.x + t1.x; v1.y = v1.y * s1.y + t1.y;
            v1.z = v1.z * s1.z + t1.z; v1.w = v1.w * s1.w + t1.w;
        }
        bf16x8 a;
        a[0] = (short)f2bf(v0.x); a[1] = (short)f2bf(v0.y);
        a[2] = (short)f2bf(v0.z); a[3] = (short)f2bf(v0.w);
        a[4] = (short)f2bf(v1.x); a[5] = (short)f2bf(v1.y);
        a[6] = (short)f2bf(v1.z); a[7] = (short)f2bf(v1.w);
#pragma unroll
        for (int ntl = 0; ntl < 4; ++ntl)
            acc[ntl] = __builtin_amdgcn_mfma_f32_16x16x32_bf16(a, bfr[ntl], acc[ntl], 0, 0, 0);
    }

    // ---- epilogue: C store + logits for this wave's 2 heads ----
    float asv[4], adv[4];
#pragma unroll
    for (int ntl = 0; ntl < 4; ++ntl) {
        asv[ntl] = a_src[(wave * 4 + ntl) * 16 + m];
        adv[ntl] = a_dst[(wave * 4 + ntl) * 16 + m];
    }
#pragma unroll
    for (int r = 0; r < 4; ++r) {
        int grow = rbase + q * 4 + r;
#pragma unroll
        for (int ntl = 0; ntl < 4; ++ntl)
            C[(size_t)grow * HC + (wave * 4 + ntl) * 16 + m] = f2bf(acc[ntl][r]);
        // local head hp in {0,1}: global head = 2*wave + hp, tiles (2hp, 2hp+1)
#pragma unroll
        for (int hp = 0; hp < 2; ++hp) {
            float ps = acc[2 * hp][r] * asv[2 * hp] + acc[2 * hp + 1][r] * asv[2 * hp + 1];
            float pd = acc[2 * hp][r] * adv[2 * hp] + acc[2 * hp + 1][r] * adv[2 * hp + 1];
            ps += __shfl_xor(ps, 1); pd += __shfl_xor(pd, 1);
            ps += __shfl_xor(ps, 2); pd += __shfl_xor(pd, 2);
            ps += __shfl_xor(ps, 4); pd += __shfl_xor(pd, 4);
            ps += __shfl_xor(ps, 8); pd += __shfl_xor(pd, 8);
            if (m == hp) {
                int head = 2 * wave + hp;
                al_s[grow * HEADS + head] = ps;
                al_d[grow * HEADS + head] = pd;
            }
        }
    }
}

// ---------------- CSR build (by dst) ----------------
__global__ void deg_kernel(const int* __restrict__ ei, int* __restrict__ deg) {
    int e = blockIdx.x * blockDim.x + threadIdx.x;
    if (e >= EP) return;
    int d = (e < E_EDGES) ? ei[E_EDGES + e] : e - E_EDGES;
    atomicAdd(deg + d, 1);
}

__global__ __launch_bounds__(1024) void scan_blk(const int* __restrict__ deg,
                                                 int* __restrict__ rs,
                                                 int* __restrict__ bsum) {
    __shared__ int sh[1024];
    int t = threadIdx.x;
    int i = blockIdx.x * 1024 + t;
    int v = (i < N_NODES) ? deg[i] : 0;
    sh[t] = v;
    __syncthreads();
    for (int off = 1; off < 1024; off <<= 1) {
        int tv = (t >= off) ? sh[t - off] : 0;
        __syncthreads();
        sh[t] += tv;
        __syncthreads();
    }
    if (i < N_NODES) rs[i] = sh[t] - v;
    if (t == 1023) bsum[blockIdx.x] = sh[1023];
}

__global__ void scan_top(int* __restrict__ bsum) {
    int t = threadIdx.x;
    int v = (t < SCAN_NB) ? bsum[t] : 0;
    int s = v;
#pragma unroll
    for (int off = 1; off < 64; off <<= 1) {
        int u = __shfl_up(s, off);
        if (t >= off) s += u;
    }
    if (t < SCAN_NB) bsum[t] = s - v;
    if (t == SCAN_NB - 1) bsum[SCAN_NB] = s;
}

__global__ __launch_bounds__(1024) void scan_add(int* __restrict__ rs,
                                                 int* __restrict__ cursor,
                                                 const int* __restrict__ bsum) {
    int i = blockIdx.x * 1024 + threadIdx.x;
    if (i < N_NODES) {
        int v = rs[i] + bsum[blockIdx.x];
        rs[i] = v;
        cursor[i] = v;
    } else if (i == N_NODES) {
        rs[N_NODES] = bsum[SCAN_NB];
    }
}

__global__ void scatter_kernel(const int* __restrict__ ei, int* __restrict__ cursor,
                               int* __restrict__ csr_src) {
    int e = blockIdx.x * blockDim.x + threadIdx.x;
    if (e >= EP) return;
    int s, d;
    if (e < E_EDGES) { s = ei[e]; d = ei[E_EDGES + e]; } else { s = d = e - E_EDGES; }
    int pos = atomicAdd(cursor + d, 1);
    csr_src[pos] = s;
}

// ---------------- fused softmax + aggregation + bias + ELU -> bf16 out ----------------
__global__ __launch_bounds__(256) void attn_kernel(const ushort4* __restrict__ h4,
                                                   const float* __restrict__ al_s,
                                                   const float* __restrict__ al_d,
                                                   const int* __restrict__ row_start,
                                                   const int* __restrict__ csr_src,
                                                   const float4* __restrict__ bias4,
                                                   ushort4* __restrict__ out4) {
    int d = blockIdx.x * 4 + (threadIdx.x >> 6);
    int lane = threadIdx.x & 63;
    int hh = lane & 7, eo = lane >> 3;
    int head = lane >> 3;
    int beg = row_start[d], end = row_start[d + 1];
    float ad = al_d[d * HEADS + hh];
    float ssum = 0.f;
    float4 acc = make_float4(0.f, 0.f, 0.f, 0.f);

    int i = beg;
    for (; i + 8 <= end; i += 8) {
        int sreg = csr_src[i + eo];
        float ex = __expf(lrelu_f(al_s[sreg * HEADS + hh] + ad));
        ssum += ex;
#pragma unroll
        for (int j = 0; j < 8; ++j) {
            int sj = __shfl(sreg, j * 8);
            float aj = __shfl(ex, j * 8 + head);
            ushort4 v = h4[(size_t)sj * 64 + lane];
            acc.x += aj * bf2f(v.x);
            acc.y += aj * bf2f(v.y);
            acc.z += aj * bf2f(v.z);
            acc.w += aj * bf2f(v.w);
        }
    }
    if (i < end) {
        int rem = end - i;
        int sreg = 0;
        float ex = 0.f;
        if (eo < rem) {
            sreg = csr_src[i + eo];
            ex = __expf(lrelu_f(al_s[sreg * HEADS + hh] + ad));
        }
        ssum += ex;
        for (int j = 0; j < rem; ++j) {
            int sj = __shfl(sreg, j * 8);
            float aj = __shfl(ex, j * 8 + head);
            ushort4 v = h4[(size_t)sj * 64 + lane];
            acc.x += aj * bf2f(v.x);
            acc.y += aj * bf2f(v.y);
            acc.z += aj * bf2f(v.z);
            acc.w += aj * bf2f(v.w);
        }
    }
    ssum += __shfl_xor(ssum, 8);
    ssum += __shfl_xor(ssum, 16);
    ssum += __shfl_xor(ssum, 32);
    float inv = 1.f / __shfl(ssum, head);

    float4 b = bias4[lane];
    ushort4 o;
    o.x = f2bf(elu_f(acc.x * inv + b.x));
    o.y = f2bf(elu_f(acc.y * inv + b.y));
    o.z = f2bf(elu_f(acc.z * inv + b.z));
    o.w = f2bf(elu_f(acc.w * inv + b.w));
    out4[(size_t)d * 64 + lane] = o;
}

// ---------------- BN stats: per-block partials (bf16 in, no atomics) ----------------
__global__ __launch_bounds__(256) void bnstat_kernel(const unsigned short* __restrict__ buf,
                                                     float* __restrict__ part) {
    int c = threadIdx.x;
    int r0 = blockIdx.x * BN_ROWS;
    int rend = min(r0 + BN_ROWS, N_NODES);
    float s = 0.f, q = 0.f;
    for (int r = r0; r < rend; ++r) {
        float v = bf2f(buf[(size_t)r * HC + c]);
        s += v;
        q += v * v;
    }
    part[(size_t)blockIdx.x * HC + c] = s;
    part[(size_t)(BN_NBLK + blockIdx.x) * HC + c] = q;
}

__global__ void bn_fin_kernel(const float* __restrict__ part,
                              const float* __restrict__ g, const float* __restrict__ be,
                              float* __restrict__ scale, float* __restrict__ shift) {
    int c = threadIdx.x;
    float s = 0.f, q = 0.f;
    for (int b = 0; b < BN_NBLK; ++b) {
        s += part[(size_t)b * HC + c];
        q += part[(size_t)(BN_NBLK + b) * HC + c];
    }
    float m = s / (float)N_NODES;
    float var = q / (float)N_NODES - m * m;
    float istd = rsqrtf(var + BN_EPS);
    float sc = istd * g[c];
    scale[c] = sc;
    shift[c] = be[c] - m * sc;
}

// ---------------- MLP head via MFMA (bf16 in, BN fused) ----------------
__global__ __launch_bounds__(256) void mlp_mfma(const unsigned short* __restrict__ in,
                                                const float* __restrict__ sc,
                                                const float* __restrict__ sh,
                                                const unsigned short* __restrict__ Wt,
                                                const float* __restrict__ lb1,
                                                const float* __restrict__ lW2,
                                                const float* __restrict__ lb2,
                                                float* __restrict__ out) {
    int tid = threadIdx.x;
    int wave = tid >> 6, lane = tid & 63;
    int m = lane & 15, q = lane >> 4;
    int rbase = blockIdx.x * 64 + wave * 16;
    int arow = rbase + m;
    bool valid = arow < N_NODES;
    const unsigned short* ap = in + (size_t)arow * HC;
    f32x4 acc0 = (f32x4){0.f, 0.f, 0.f, 0.f}, acc1 = acc0;
#pragma unroll
    for (int k0 = 0; k0 < HC; k0 += 32) {
        int c0 = k0 + q * 8;
        bf16x8 b0 = *(const bf16x8*)(Wt + (size_t)m * HC + c0);
        bf16x8 b1 = *(const bf16x8*)(Wt + (size_t)(m + 16) * HC + c0);
        bf16x8 a = (bf16x8){0, 0, 0, 0, 0, 0, 0, 0};
        if (valid) {
            uint4 raw = *(const uint4*)(ap + c0);
            float v0 = bf2f((unsigned short)raw.x), v1 = bf2f((unsigned short)(raw.x >> 16));
            float v2 = bf2f((unsigned short)raw.y), v3 = bf2f((unsigned short)(raw.y >> 16));
            float v4 = bf2f((unsigned short)raw.z), v5 = bf2f((unsigned short)(raw.z >> 16));
            float v6 = bf2f((unsigned short)raw.w), v7 = bf2f((unsigned short)(raw.w >> 16));
            float4 s0 = *(const float4*)(sc + c0), s1 = *(const float4*)(sc + c0 + 4);
            float4 t0 = *(const float4*)(sh + c0), t1 = *(const float4*)(sh + c0 + 4);
            a[0] = (short)f2bf(v0 * s0.x + t0.x);
            a[1] = (short)f2bf(v1 * s0.y + t0.y);
            a[2] = (short)f2bf(v2 * s0.z + t0.z);
            a[3] = (short)f2bf(v3 * s0.w + t0.w);
            a[4] = (short)f2bf(v4 * s1.x + t1.x);
            a[5] = (short)f2bf(v5 * s1.y + t1.y);
            a[6] = (short)f2bf(v6 * s1.z + t1.z);
            a[7] = (short)f2bf(v7 * s1.w + t1.w);
        }
        acc0 = __builtin_amdgcn_mfma_f32_16x16x32_bf16(a, b0, acc0, 0, 0, 0);
        acc1 = __builtin_amdgcn_mfma_f32_16x16x32_bf16(a, b1, acc1, 0, 0, 0);
    }
    float w2a = lW2[m], w2b = lW2[m + 16];
    float ba = lb1[m], bb = lb1[m + 16];
#pragma unroll
    for (int r = 0; r < 4; ++r) {
        float v = elu_f(acc0[r] + ba) * w2a + elu_f(acc1[r] + bb) * w2b;
        v += __shfl_xor(v, 1);
        v += __shfl_xor(v, 2);
        v += __shfl_xor(v, 4);
        v += __shfl_xor(v, 8);
        int orow = rbase + q * 4 + r;
        if (m == 0 && orow < N_NODES) out[orow] = v + lb2[0];
    }
}

extern "C" void kernel_launch(void* const* d_in, const int* in_sizes, int n_in,
                              void* d_out, int out_size, void* d_ws, size_t ws_size,
                              hipStream_t stream) {
    const float* x   = (const float*)d_in[0];
    const int*   ei  = (const int*)d_in[1];
    const float* W1  = (const float*)d_in[2];
    const float* a1s = (const float*)d_in[3];
    const float* a1d = (const float*)d_in[4];
    const float* b1  = (const float*)d_in[5];
    const float* g1  = (const float*)d_in[6];
    const float* be1 = (const float*)d_in[7];
    const float* W2  = (const float*)d_in[8];
    const float* a2s = (const float*)d_in[9];
    const float* a2d = (const float*)d_in[10];
    const float* b2  = (const float*)d_in[11];
    const float* g2  = (const float*)d_in[12];
    const float* be2 = (const float*)d_in[13];
    const float* lW1 = (const float*)d_in[14];
    const float* lb1 = (const float*)d_in[15];
    const float* lW2 = (const float*)d_in[16];
    const float* lb2 = (const float*)d_in[17];
    float* out = (float*)d_out;

    char* p = (char*)d_ws;
    auto alloc = [&](size_t bytes) {
        char* r = p;
        p += (bytes + 255) & ~(size_t)255;
        return r;
    };
    unsigned short* h_bf  = (unsigned short*)alloc((size_t)N_NODES * HC * 2);
    unsigned short* o_bf  = (unsigned short*)alloc((size_t)N_NODES * HC * 2);
    unsigned short* wt1   = (unsigned short*)alloc((size_t)IN_CH * HC * 2);
    unsigned short* wt2   = (unsigned short*)alloc((size_t)HC * HC * 2);
    unsigned short* wtm   = (unsigned short*)alloc((size_t)HC * HID * 2);
    float* f_als  = (float*)alloc((size_t)N_NODES * HEADS * 4);
    float* f_ald  = (float*)alloc((size_t)N_NODES * HEADS * 4);
    int*   i_deg  = (int*)alloc((size_t)N_NODES * 4);
    int*   i_rs   = (int*)alloc((size_t)(N_NODES + 1) * 4);
    int*   i_cur  = (int*)alloc((size_t)N_NODES * 4);
    int*   i_src  = (int*)alloc((size_t)EP * 4);
    int*   i_bsum = (int*)alloc((size_t)(SCAN_NB + 1) * 4);
    float* f_part = (float*)alloc((size_t)2 * BN_NBLK * HC * 4);
    float* f_sc1  = (float*)alloc(HC * 4);
    float* f_sh1  = (float*)alloc(HC * 4);
    float* f_sc2  = (float*)alloc(HC * 4);
    float* f_sh2  = (float*)alloc(HC * 4);

    int eb = (EP + 255) / 256;

    // ---- CSR build (same graph both layers) ----
    hipMemsetAsync(i_deg, 0, (size_t)N_NODES * 4, stream);
    deg_kernel<<<eb, 256, 0, stream>>>(ei, i_deg);
    scan_blk<<<SCAN_NB, 1024, 0, stream>>>(i_deg, i_rs, i_bsum);
    scan_top<<<1, 64, 0, stream>>>(i_bsum);
    scan_add<<<SCAN_NB, 1024, 0, stream>>>(i_rs, i_cur, i_bsum);
    scatter_kernel<<<eb, 256, 0, stream>>>(ei, i_cur, i_src);

    // ---- all weight conversions, one dispatch ----
    int wtot = IN_CH * HC + HC * HC + HC * HID;
    wt_all_kernel<<<(wtot + 255) / 256, 256, 0, stream>>>(W1, W2, lW1, wt1, wt2, wtm);

    int gblocks16 = N_NODES / 16;  // 1875
    int gblocks64 = (N_NODES + 63) / 64;

    auto run_layer = [&](const float* A32, const unsigned short* Abf, int K,
                         const unsigned short* wt, const float* in_sc, const float* in_sh,
                         const float* as_, const float* ad_, const float* bias,
                         const float* gam, const float* bet, float* out_sc,
                         float* out_sh) {
        gemm_direct<<<gblocks16, 256, 0, stream>>>(A32, Abf, wt, h_bf, f_als, f_ald, as_, ad_,
                                                   N_NODES, K, in_sc, in_sh);
        attn_kernel<<<N_NODES / 4, 256, 0, stream>>>((const ushort4*)h_bf, f_als, f_ald,
                                                     i_rs, i_src, (const float4*)bias,
                                                     (ushort4*)o_bf);
        bnstat_kernel<<<BN_NBLK, 256, 0, stream>>>(o_bf, f_part);
        bn_fin_kernel<<<1, 256, 0, stream>>>(f_part, gam, bet, out_sc, out_sh);
    };

    run_layer(x, nullptr, IN_CH, wt1, nullptr, nullptr, a1s, a1d, b1, g1, be1, f_sc1, f_sh1);
    run_layer(nullptr, o_bf, HC, wt2, f_sc1, f_sh1, a2s, a2d, b2, g2, be2, f_sc2, f_sh2);

    mlp_mfma<<<gblocks64, 256, 0, stream>>>(o_bf, f_sc2, f_sh2, wtm, lb1, lW2, lb2, out);
}

// Round 12
// 382.719 us; speedup vs baseline: 1.0913x; 1.0913x over previous
//
#include <hip/hip_runtime.h>
#include <math.h>

#define N_NODES 30000
#define E_EDGES 480000
#define EP (E_EDGES + N_NODES) /* 510000 edges incl self loops */
#define IN_CH 128
#define HID 32
#define HEADS 8
#define HC 256
#define BN_EPS 1e-5f
#define NEG_SLOPE 0.2f
#define SCAN_NB ((N_NODES + 1023) / 1024) /* 30 */
#define BN_ROWS 128
#define BN_NBLK ((N_NODES + BN_ROWS - 1) / BN_ROWS) /* 235 */

typedef __attribute__((ext_vector_type(8))) short bf16x8;
typedef __attribute__((ext_vector_type(4))) float f32x4;

__device__ __forceinline__ float elu_f(float x) { return x > 0.f ? x : __expf(x) - 1.f; }
__device__ __forceinline__ float lrelu_f(float x) { return x >= 0.f ? x : NEG_SLOPE * x; }
__device__ __forceinline__ float bf2f(unsigned short u) {
    return __uint_as_float(((unsigned)u) << 16);
}
__device__ __forceinline__ unsigned short f2bf(float f) {
    unsigned u = __float_as_uint(f);
    return (unsigned short)((u + 0x7fffu + ((u >> 16) & 1u)) >> 16);
}

// ---------------- all weights fp32 -> bf16 transposed, one dispatch ----------------
__global__ void wt_all_kernel(const float* __restrict__ W1, const float* __restrict__ W2,
                              const float* __restrict__ lW1,
                              unsigned short* __restrict__ wt1,
                              unsigned short* __restrict__ wt2,
                              unsigned short* __restrict__ wtm) {
    int i = blockIdx.x * 256 + threadIdx.x;
    if (i < IN_CH * HC) {
        int k = i >> 8, n = i & 255;
        wt1[(size_t)n * IN_CH + k] = f2bf(W1[i]);
    } else if (i < IN_CH * HC + HC * HC) {
        int j = i - IN_CH * HC;
        int k = j >> 8, n = j & 255;
        wt2[(size_t)n * HC + k] = f2bf(W2[j]);
    } else if (i < IN_CH * HC + HC * HC + HC * HID) {
        int j = i - IN_CH * HC - HC * HC;
        int k = j >> 5, n = j & 31;
        wtm[(size_t)n * HC + k] = f2bf(lW1[j]);
    }
}

// ---------------- LDS-staged MFMA GEMM + fused al epilogue ----------------
// C[M,256] = BN(A[M,K]) * Wt^T; al_s/al_d logits computed in the epilogue
// (kills the separate al_kernel pass over h).
// block = 256 thr = 4 waves; tile 64(M) x 256(N), BK=32. LDS rows padded to 40
// (2-way bank alias only = free). REVERTED from the R9-R11 direct-fragment line:
// L2-direct fragment fetch is address-divergent and latency-serial (MfmaUtil
// stuck at 2.7% across 3 variants); LDS staging amortizes it.
__global__ __launch_bounds__(256) void gemm_mfma(const float* __restrict__ A32,
                                                 const unsigned short* __restrict__ Abf,
                                                 const unsigned short* __restrict__ Bt,
                                                 unsigned short* __restrict__ C,
                                                 float* __restrict__ al_s,
                                                 float* __restrict__ al_d,
                                                 const float* __restrict__ a_src,
                                                 const float* __restrict__ a_dst,
                                                 int M, int K,
                                                 const float* __restrict__ sc,
                                                 const float* __restrict__ sh) {
    __shared__ __align__(16) unsigned short As[64][40];
    __shared__ __align__(16) unsigned short Bs[256][40];
    int tid = threadIdx.x;
    int wave = tid >> 6, lane = tid & 63;
    int m = lane & 15, q = lane >> 4;
    int row0 = blockIdx.x * 64;
    f32x4 acc[16];
#pragma unroll
    for (int i = 0; i < 16; ++i) acc[i] = (f32x4){0.f, 0.f, 0.f, 0.f};
    int ar = tid >> 2, aseg = tid & 3;
    for (int k0 = 0; k0 < K; k0 += 32) {
        float4 v0 = make_float4(0.f, 0.f, 0.f, 0.f), v1 = v0;
        int gr = row0 + ar;
        int c0 = k0 + aseg * 8;
        if (gr < M) {
            if (A32) {
                const float* ap = A32 + (size_t)gr * K + c0;
                v0 = *(const float4*)ap;
                v1 = *(const float4*)(ap + 4);
            } else {
                uint4 raw = *(const uint4*)(Abf + (size_t)gr * K + c0);
                v0.x = bf2f((unsigned short)raw.x); v0.y = bf2f((unsigned short)(raw.x >> 16));
                v0.z = bf2f((unsigned short)raw.y); v0.w = bf2f((unsigned short)(raw.y >> 16));
                v1.x = bf2f((unsigned short)raw.z); v1.y = bf2f((unsigned short)(raw.z >> 16));
                v1.z = bf2f((unsigned short)raw.w); v1.w = bf2f((unsigned short)(raw.w >> 16));
            }
        }
        if (sc) {
            float4 s0 = *(const float4*)(sc + c0), s1 = *(const float4*)(sc + c0 + 4);
            float4 t0 = *(const float4*)(sh + c0), t1 = *(const float4*)(sh + c0 + 4);
            v0.x = v0.x * s0.x + t0.x; v0.y = v0.y * s0.y + t0.y;
            v0.z = v0.z * s0.z + t0.z; v0.w = v0.w * s0.w + t0.w;
            v1.x = v1.x * s1.x + t1.x; v1.y = v1.y * s1.y + t1.y;
            v1.z = v1.z * s1.z + t1.z; v1.w = v1.w * s1.w + t1.w;
        }
        bf16x8 av;
        av[0] = (short)f2bf(v0.x); av[1] = (short)f2bf(v0.y);
        av[2] = (short)f2bf(v0.z); av[3] = (short)f2bf(v0.w);
        av[4] = (short)f2bf(v1.x); av[5] = (short)f2bf(v1.y);
        av[6] = (short)f2bf(v1.z); av[7] = (short)f2bf(v1.w);
        *(bf16x8*)(&As[ar][aseg * 8]) = av;
        const unsigned short* bp = Bt + (size_t)tid * K + k0;
#pragma unroll
        for (int sg = 0; sg < 4; ++sg)
            *(uint4*)(&Bs[tid][sg * 8]) = *(const uint4*)(bp + sg * 8);
        __syncthreads();
        bf16x8 a = *(const bf16x8*)(&As[wave * 16 + m][q * 8]);
#pragma unroll
        for (int nt = 0; nt < 16; ++nt) {
            bf16x8 b = *(const bf16x8*)(&Bs[nt * 16 + m][q * 8]);
            acc[nt] = __builtin_amdgcn_mfma_f32_16x16x32_bf16(a, b, acc[nt], 0, 0, 0);
        }
        __syncthreads();
    }
    // ---- epilogue: C store + per-head logits (head h = col tiles 2h,2h+1) ----
    int rbase = row0 + wave * 16;
    float asv[16], adv[16];
#pragma unroll
    for (int nt = 0; nt < 16; ++nt) {
        asv[nt] = a_src[nt * 16 + m];
        adv[nt] = a_dst[nt * 16 + m];
    }
#pragma unroll
    for (int r = 0; r < 4; ++r) {
        int grow = rbase + q * 4 + r;
        bool gv = grow < M;
        if (gv) {
#pragma unroll
            for (int nt = 0; nt < 16; ++nt)
                C[(size_t)grow * HC + nt * 16 + m] = f2bf(acc[nt][r]);
        }
#pragma unroll
        for (int h = 0; h < HEADS; ++h) {
            float ps = acc[2 * h][r] * asv[2 * h] + acc[2 * h + 1][r] * asv[2 * h + 1];
            float pd = acc[2 * h][r] * adv[2 * h] + acc[2 * h + 1][r] * adv[2 * h + 1];
            ps += __shfl_xor(ps, 1); pd += __shfl_xor(pd, 1);
            ps += __shfl_xor(ps, 2); pd += __shfl_xor(pd, 2);
            ps += __shfl_xor(ps, 4); pd += __shfl_xor(pd, 4);
            ps += __shfl_xor(ps, 8); pd += __shfl_xor(pd, 8);
            if (m == h && gv) {
                al_s[grow * HEADS + h] = ps;
                al_d[grow * HEADS + h] = pd;
            }
        }
    }
}

// ---------------- CSR build (by dst) ----------------
__global__ void deg_kernel(const int* __restrict__ ei, int* __restrict__ deg) {
    int e = blockIdx.x * blockDim.x + threadIdx.x;
    if (e >= EP) return;
    int d = (e < E_EDGES) ? ei[E_EDGES + e] : e - E_EDGES;
    atomicAdd(deg + d, 1);
}

__global__ __launch_bounds__(1024) void scan_blk(const int* __restrict__ deg,
                                                 int* __restrict__ rs,
                                                 int* __restrict__ bsum) {
    __shared__ int sh[1024];
    int t = threadIdx.x;
    int i = blockIdx.x * 1024 + t;
    int v = (i < N_NODES) ? deg[i] : 0;
    sh[t] = v;
    __syncthreads();
    for (int off = 1; off < 1024; off <<= 1) {
        int tv = (t >= off) ? sh[t - off] : 0;
        __syncthreads();
        sh[t] += tv;
        __syncthreads();
    }
    if (i < N_NODES) rs[i] = sh[t] - v;
    if (t == 1023) bsum[blockIdx.x] = sh[1023];
}

__global__ void scan_top(int* __restrict__ bsum) {
    int t = threadIdx.x;
    int v = (t < SCAN_NB) ? bsum[t] : 0;
    int s = v;
#pragma unroll
    for (int off = 1; off < 64; off <<= 1) {
        int u = __shfl_up(s, off);
        if (t >= off) s += u;
    }
    if (t < SCAN_NB) bsum[t] = s - v;
    if (t == SCAN_NB - 1) bsum[SCAN_NB] = s;
}

__global__ __launch_bounds__(1024) void scan_add(int* __restrict__ rs,
                                                 int* __restrict__ cursor,
                                                 const int* __restrict__ bsum) {
    int i = blockIdx.x * 1024 + threadIdx.x;
    if (i < N_NODES) {
        int v = rs[i] + bsum[blockIdx.x];
        rs[i] = v;
        cursor[i] = v;
    } else if (i == N_NODES) {
        rs[N_NODES] = bsum[SCAN_NB];
    }
}

__global__ void scatter_kernel(const int* __restrict__ ei, int* __restrict__ cursor,
                               int* __restrict__ csr_src) {
    int e = blockIdx.x * blockDim.x + threadIdx.x;
    if (e >= EP) return;
    int s, d;
    if (e < E_EDGES) { s = ei[e]; d = ei[E_EDGES + e]; } else { s = d = e - E_EDGES; }
    int pos = atomicAdd(cursor + d, 1);
    csr_src[pos] = s;
}

// ---------------- fused softmax + aggregation + bias + ELU -> bf16 out ----------------
__global__ __launch_bounds__(256) void attn_kernel(const ushort4* __restrict__ h4,
                                                   const float* __restrict__ al_s,
                                                   const float* __restrict__ al_d,
                                                   const int* __restrict__ row_start,
                                                   const int* __restrict__ csr_src,
                                                   const float4* __restrict__ bias4,
                                                   ushort4* __restrict__ out4) {
    int d = blockIdx.x * 4 + (threadIdx.x >> 6);
    int lane = threadIdx.x & 63;
    int hh = lane & 7, eo = lane >> 3;
    int head = lane >> 3;
    int beg = row_start[d], end = row_start[d + 1];
    float ad = al_d[d * HEADS + hh];
    float ssum = 0.f;
    float4 acc = make_float4(0.f, 0.f, 0.f, 0.f);

    int i = beg;
    for (; i + 8 <= end; i += 8) {
        int sreg = csr_src[i + eo];
        float ex = __expf(lrelu_f(al_s[sreg * HEADS + hh] + ad));
        ssum += ex;
#pragma unroll
        for (int j = 0; j < 8; ++j) {
            int sj = __shfl(sreg, j * 8);
            float aj = __shfl(ex, j * 8 + head);
            ushort4 v = h4[(size_t)sj * 64 + lane];
            acc.x += aj * bf2f(v.x);
            acc.y += aj * bf2f(v.y);
            acc.z += aj * bf2f(v.z);
            acc.w += aj * bf2f(v.w);
        }
    }
    if (i < end) {
        int rem = end - i;
        int sreg = 0;
        float ex = 0.f;
        if (eo < rem) {
            sreg = csr_src[i + eo];
            ex = __expf(lrelu_f(al_s[sreg * HEADS + hh] + ad));
        }
        ssum += ex;
        for (int j = 0; j < rem; ++j) {
            int sj = __shfl(sreg, j * 8);
            float aj = __shfl(ex, j * 8 + head);
            ushort4 v = h4[(size_t)sj * 64 + lane];
            acc.x += aj * bf2f(v.x);
            acc.y += aj * bf2f(v.y);
            acc.z += aj * bf2f(v.z);
            acc.w += aj * bf2f(v.w);
        }
    }
    ssum += __shfl_xor(ssum, 8);
    ssum += __shfl_xor(ssum, 16);
    ssum += __shfl_xor(ssum, 32);
    float inv = 1.f / __shfl(ssum, head);

    float4 b = bias4[lane];
    ushort4 o;
    o.x = f2bf(elu_f(acc.x * inv + b.x));
    o.y = f2bf(elu_f(acc.y * inv + b.y));
    o.z = f2bf(elu_f(acc.z * inv + b.z));
    o.w = f2bf(elu_f(acc.w * inv + b.w));
    out4[(size_t)d * 64 + lane] = o;
}

// ---------------- BN stats: per-block partials (bf16 in, no atomics) ----------------
__global__ __launch_bounds__(256) void bnstat_kernel(const unsigned short* __restrict__ buf,
                                                     float* __restrict__ part) {
    int c = threadIdx.x;
    int r0 = blockIdx.x * BN_ROWS;
    int rend = min(r0 + BN_ROWS, N_NODES);
    float s = 0.f, q = 0.f;
    for (int r = r0; r < rend; ++r) {
        float v = bf2f(buf[(size_t)r * HC + c]);
        s += v;
        q += v * v;
    }
    part[(size_t)blockIdx.x * HC + c] = s;
    part[(size_t)(BN_NBLK + blockIdx.x) * HC + c] = q;
}

__global__ void bn_fin_kernel(const float* __restrict__ part,
                              const float* __restrict__ g, const float* __restrict__ be,
                              float* __restrict__ scale, float* __restrict__ shift) {
    int c = threadIdx.x;
    float s = 0.f, q = 0.f;
    for (int b = 0; b < BN_NBLK; ++b) {
        s += part[(size_t)b * HC + c];
        q += part[(size_t)(BN_NBLK + b) * HC + c];
    }
    float m = s / (float)N_NODES;
    float var = q / (float)N_NODES - m * m;
    float istd = rsqrtf(var + BN_EPS);
    float sc = istd * g[c];
    scale[c] = sc;
    shift[c] = be[c] - m * sc;
}

// ---------------- MLP head via MFMA (bf16 in, BN fused) ----------------
__global__ __launch_bounds__(256) void mlp_mfma(const unsigned short* __restrict__ in,
                                                const float* __restrict__ sc,
                                                const float* __restrict__ sh,
                                                const unsigned short* __restrict__ Wt,
                                                const float* __restrict__ lb1,
                                                const float* __restrict__ lW2,
                                                const float* __restrict__ lb2,
                                                float* __restrict__ out) {
    int tid = threadIdx.x;
    int wave = tid >> 6, lane = tid & 63;
    int m = lane & 15, q = lane >> 4;
    int rbase = blockIdx.x * 64 + wave * 16;
    int arow = rbase + m;
    bool valid = arow < N_NODES;
    const unsigned short* ap = in + (size_t)arow * HC;
    f32x4 acc0 = (f32x4){0.f, 0.f, 0.f, 0.f}, acc1 = acc0;
#pragma unroll
    for (int k0 = 0; k0 < HC; k0 += 32) {
        int c0 = k0 + q * 8;
        bf16x8 b0 = *(const bf16x8*)(Wt + (size_t)m * HC + c0);
        bf16x8 b1 = *(const bf16x8*)(Wt + (size_t)(m + 16) * HC + c0);
        bf16x8 a = (bf16x8){0, 0, 0, 0, 0, 0, 0, 0};
        if (valid) {
            uint4 raw = *(const uint4*)(ap + c0);
            float v0 = bf2f((unsigned short)raw.x), v1 = bf2f((unsigned short)(raw.x >> 16));
            float v2 = bf2f((unsigned short)raw.y), v3 = bf2f((unsigned short)(raw.y >> 16));
            float v4 = bf2f((unsigned short)raw.z), v5 = bf2f((unsigned short)(raw.z >> 16));
            float v6 = bf2f((unsigned short)raw.w), v7 = bf2f((unsigned short)(raw.w >> 16));
            float4 s0 = *(const float4*)(sc + c0), s1 = *(const float4*)(sc + c0 + 4);
            float4 t0 = *(const float4*)(sh + c0), t1 = *(const float4*)(sh + c0 + 4);
            a[0] = (short)f2bf(v0 * s0.x + t0.x);
            a[1] = (short)f2bf(v1 * s0.y + t0.y);
            a[2] = (short)f2bf(v2 * s0.z + t0.z);
            a[3] = (short)f2bf(v3 * s0.w + t0.w);
            a[4] = (short)f2bf(v4 * s1.x + t1.x);
            a[5] = (short)f2bf(v5 * s1.y + t1.y);
            a[6] = (short)f2bf(v6 * s1.z + t1.z);
            a[7] = (short)f2bf(v7 * s1.w + t1.w);
        }
        acc0 = __builtin_amdgcn_mfma_f32_16x16x32_bf16(a, b0, acc0, 0, 0, 0);
        acc1 = __builtin_amdgcn_mfma_f32_16x16x32_bf16(a, b1, acc1, 0, 0, 0);
    }
    float w2a = lW2[m], w2b = lW2[m + 16];
    float ba = lb1[m], bb = lb1[m + 16];
#pragma unroll
    for (int r = 0; r < 4; ++r) {
        float v = elu_f(acc0[r] + ba) * w2a + elu_f(acc1[r] + bb) * w2b;
        v += __shfl_xor(v, 1);
        v += __shfl_xor(v, 2);
        v += __shfl_xor(v, 4);
        v += __shfl_xor(v, 8);
        int orow = rbase + q * 4 + r;
        if (m == 0 && orow < N_NODES) out[orow] = v + lb2[0];
    }
}

extern "C" void kernel_launch(void* const* d_in, const int* in_sizes, int n_in,
                              void* d_out, int out_size, void* d_ws, size_t ws_size,
                              hipStream_t stream) {
    const float* x   = (const float*)d_in[0];
    const int*   ei  = (const int*)d_in[1];
    const float* W1  = (const float*)d_in[2];
    const float* a1s = (const float*)d_in[3];
    const float* a1d = (const float*)d_in[4];
    const float* b1  = (const float*)d_in[5];
    const float* g1  = (const float*)d_in[6];
    const float* be1 = (const float*)d_in[7];
    const float* W2  = (const float*)d_in[8];
    const float* a2s = (const float*)d_in[9];
    const float* a2d = (const float*)d_in[10];
    const float* b2  = (const float*)d_in[11];
    const float* g2  = (const float*)d_in[12];
    const float* be2 = (const float*)d_in[13];
    const float* lW1 = (const float*)d_in[14];
    const float* lb1 = (const float*)d_in[15];
    const float* lW2 = (const float*)d_in[16];
    const float* lb2 = (const float*)d_in[17];
    float* out = (float*)d_out;

    char* p = (char*)d_ws;
    auto alloc = [&](size_t bytes) {
        char* r = p;
        p += (bytes + 255) & ~(size_t)255;
        return r;
    };
    unsigned short* h_bf  = (unsigned short*)alloc((size_t)N_NODES * HC * 2);
    unsigned short* o_bf  = (unsigned short*)alloc((size_t)N_NODES * HC * 2);
    unsigned short* wt1   = (unsigned short*)alloc((size_t)IN_CH * HC * 2);
    unsigned short* wt2   = (unsigned short*)alloc((size_t)HC * HC * 2);
    unsigned short* wtm   = (unsigned short*)alloc((size_t)HC * HID * 2);
    float* f_als  = (float*)alloc((size_t)N_NODES * HEADS * 4);
    float* f_ald  = (float*)alloc((size_t)N_NODES * HEADS * 4);
    int*   i_deg  = (int*)alloc((size_t)N_NODES * 4);
    int*   i_rs   = (int*)alloc((size_t)(N_NODES + 1) * 4);
    int*   i_cur  = (int*)alloc((size_t)N_NODES * 4);
    int*   i_src  = (int*)alloc((size_t)EP * 4);
    int*   i_bsum = (int*)alloc((size_t)(SCAN_NB + 1) * 4);
    float* f_part = (float*)alloc((size_t)2 * BN_NBLK * HC * 4);
    float* f_sc1  = (float*)alloc(HC * 4);
    float* f_sh1  = (float*)alloc(HC * 4);
    float* f_sc2  = (float*)alloc(HC * 4);
    float* f_sh2  = (float*)alloc(HC * 4);

    int eb = (EP + 255) / 256;

    // ---- CSR build (same graph both layers) ----
    hipMemsetAsync(i_deg, 0, (size_t)N_NODES * 4, stream);
    deg_kernel<<<eb, 256, 0, stream>>>(ei, i_deg);
    scan_blk<<<SCAN_NB, 1024, 0, stream>>>(i_deg, i_rs, i_bsum);
    scan_top<<<1, 64, 0, stream>>>(i_bsum);
    scan_add<<<SCAN_NB, 1024, 0, stream>>>(i_rs, i_cur, i_bsum);
    scatter_kernel<<<eb, 256, 0, stream>>>(ei, i_cur, i_src);

    // ---- all weight conversions, one dispatch ----
    int wtot = IN_CH * HC + HC * HC + HC * HID;
    wt_all_kernel<<<(wtot + 255) / 256, 256, 0, stream>>>(W1, W2, lW1, wt1, wt2, wtm);

    int gblocks = (N_NODES + 63) / 64;

    auto run_layer = [&](const float* A32, const unsigned short* Abf, int K,
                         const unsigned short* wt, const float* in_sc, const float* in_sh,
                         const float* as_, const float* ad_, const float* bias,
                         const float* gam, const float* bet, float* out_sc,
                         float* out_sh) {
        gemm_mfma<<<gblocks, 256, 0, stream>>>(A32, Abf, wt, h_bf, f_als, f_ald, as_, ad_,
                                               N_NODES, K, in_sc, in_sh);
        attn_kernel<<<N_NODES / 4, 256, 0, stream>>>((const ushort4*)h_bf, f_als, f_ald,
                                                     i_rs, i_src, (const float4*)bias,
                                                     (ushort4*)o_bf);
        bnstat_kernel<<<BN_NBLK, 256, 0, stream>>>(o_bf, f_part);
        bn_fin_kernel<<<1, 256, 0, stream>>>(f_part, gam, bet, out_sc, out_sh);
    };

    run_layer(x, nullptr, IN_CH, wt1, nullptr, nullptr, a1s, a1d, b1, g1, be1, f_sc1, f_sh1);
    run_layer(nullptr, o_bf, HC, wt2, f_sc1, f_sh1, a2s, a2d, b2, g2, be2, f_sc2, f_sh2);

    mlp_mfma<<<gblocks, 256, 0, stream>>>(o_bf, f_sc2, f_sh2, wtm, lb1, lW2, lb2, out);
}